// Round 10
// baseline (542.241 us; speedup 1.0000x reference)
//
#include <hip/hip_runtime.h>
#include <cstdint>

#define NCLS 3
#define NPTS 100000
#define NB 2
#define PRE 512
#define POST 100
#define SCORE_TH 0.1f
#define NMS_TH 0.25
#define CAP 1024            // candidate buffer per problem (expect ~690)
#define BPP 98              // 1024-point chunks per plane (98*1024 >= 100000)
#define NBINS 384           // fast-key bins: (key>>17) - (0xBD000000>>17)
#define BIN_SH 17
#define BIN_OFFW (0xBD000000u >> BIN_SH)
#define FMARG 2e-5f         // 2x bound on |f32 sigmoid - f64 sigmoid| (<=1e-6)
#define NPROB (NB * NCLS)
#define WAVES_PER_PROB 2304  // 36 upper-tri 64x64 cells x 64 rows
#define HPB (NCLS * NBINS)   // 1152 LDS hist entries per hist block
#define BLKS_PER_PROB 576    // K3: 2304 waves / 4 waves-per-block

// ---------------- ws layout (bytes) ----------------
// [memset 0 region: 0 .. 9,472)
// hist      : uint32 [6*384]        @ 0        (9,216)
// cand_cnt  : uint32 [6] (pad 64)   @ 9,216
// done_hist : uint32 [1] (pad 64)   @ 9,280
// done_seg  : uint32 [6] (pad 64)   @ 9,344
// done_iou  : uint32 [6] (pad 64)   @ 9,408
// [not memset]
// pivots    : uint32 [6] (pad 64)   @ 9,472
// mask      : uint64 [6*PRE*8]      @ 9,536    (196,608; upper-tri words
//                                               always stored; lower-tri
//                                               garbage provably harmless)
// cand      : uint64 [6*CAP]        @ 206,144  (49,152)
// cand_idx  : uint32 [6*PRE]        @ 255,296  (12,288)
// cand_scr  : float  [6*PRE]        @ 267,584  (12,288)
// boxdata   : double [6*PRE*20]     @ 279,872  (491,520)
// screen    : float  [6*PRE*8]      @ 771,392  (98,304)
// sf        : float  [6*NPTS]       @ 869,696  (2,400,000)  plane-major
// total ~3.27 MB

__device__ __forceinline__ uint32_t score_key(float x)
{
    // EXACT path: f64 sigmoid rounded to f32 == reference (absmax 0.0 R1-R9)
    double sd = 1.0 / (1.0 + exp(-(double)x));
    float s = (float)sd;
    if (!(s >= SCORE_TH)) s = -1.0f;
    uint32_t u = __float_as_uint(s);
    return (u & 0x80000000u) ? ~u : (u | 0x80000000u);
}

__device__ __forceinline__ float fast_sig(float x)
{
    return 1.0f / (1.0f + __expf(-x));
}

// monotone bin of a (possibly margin-adjusted) f32 score
__device__ __forceinline__ int fast_bin(float s)
{
    float v = (s >= SCORE_TH) ? s : -1.0f;
    uint32_t u = __float_as_uint(v);
    uint32_t kk = (u & 0x80000000u) ? ~u : (u | 0x80000000u);
    int b = (int)(kk >> BIN_SH) - (int)BIN_OFFW;
    return b < 0 ? 0 : (b > NBINS - 1 ? NBINS - 1 : b);
}

// K1: fast sigmoid + LDS hist -> global-atomic flush; LAST block (device
// atomic counter + threadfence) computes all 6 pivots. Replaces R8's
// hist + pivot dispatches.
__global__ __launch_bounds__(1024) void hist_pivot_kernel(
    const float* __restrict__ cls, float* __restrict__ sf,
    uint32_t* __restrict__ hist, uint32_t* __restrict__ done_hist,
    uint32_t* __restrict__ pivots)
{
    __shared__ uint32_t lh[HPB];
    __shared__ uint32_t bins[NPROB * NBINS];   // pivot phase (last block only)
    __shared__ uint32_t is_last;
    for (int t = threadIdx.x; t < HPB; t += 1024) lh[t] = 0;
    __syncthreads();
    const int b = blockIdx.x / BPP, cb = blockIdx.x % BPP;
    const int i = cb * 1024 + threadIdx.x;
    if (i < NPTS) {
        const float* cp = cls + ((size_t)b * NPTS + i) * NCLS;
        #pragma unroll
        for (int k = 0; k < NCLS; ++k) {
            float sfv = fast_sig(cp[k]);
            sf[(size_t)(b * NCLS + k) * NPTS + i] = sfv;
            atomicAdd(&lh[k * NBINS + fast_bin(sfv)], 1u);
        }
    }
    __syncthreads();
    for (int t = threadIdx.x; t < HPB; t += 1024) {
        uint32_t c = lh[t];
        if (c)
            atomicAdd(&hist[(b * NCLS + t / NBINS) * NBINS + t % NBINS], c);
    }

    __threadfence();                            // release hist writes
    if (threadIdx.x == 0)
        is_last = (atomicAdd(done_hist, 1u) == NB * BPP - 1);
    __syncthreads();
    if (!is_last) return;
    __threadfence();                            // acquire all blocks' hist

    for (int t = threadIdx.x; t < NPROB * NBINS; t += 1024) bins[t] = hist[t];
    __syncthreads();
    if (threadIdx.x < NPROB) {
        const int p = threadIdx.x;
        int cum = 0;
        uint32_t pb = 0;
        for (int bin = NBINS - 1; bin >= 0; --bin) {
            int h = (int)bins[p * NBINS + bin];
            if (cum + h >= PRE) { pb = (uint32_t)bin; break; }
            cum += h;
        }
        pivots[p] = pb;
    }
}

// K2: compact survivors; LAST segment-block of each problem runs the
// 1024-wide bitonic select + f64 geometry for that problem. Replaces R8's
// compact + select dispatches (and overlaps select with other compacts).
__global__ __launch_bounds__(1024) void compact_select_kernel(
    const float* __restrict__ cls, const float* __restrict__ boxes,
    const float* __restrict__ sf, const uint32_t* __restrict__ pivots,
    uint32_t* __restrict__ cand_cnt, unsigned long long* __restrict__ cand,
    uint32_t* __restrict__ done_seg, uint32_t* __restrict__ cand_idx,
    float* __restrict__ cand_score, double* __restrict__ boxdata,
    float* __restrict__ screen)
{
    __shared__ unsigned long long skey[CAP];    // stage, then sort keys
    __shared__ uint32_t lcnt, lbase, is_last;
    if (threadIdx.x == 0) lcnt = 0;
    __syncthreads();

    const int p = blockIdx.x / BPP, cb = blockIdx.x % BPP;
    const int tid = threadIdx.x;
    const int i = cb * 1024 + tid;
    const uint32_t pb = pivots[p];

    if (i < NPTS) {
        float sfv = sf[(size_t)p * NPTS + i];   // identical bits to K1's
        if ((uint32_t)fast_bin(sfv + FMARG) >= pb) {
            const int b = p / NCLS, k = p % NCLS;
            uint32_t kk = score_key(cls[((size_t)b * NPTS + i) * NCLS + k]);
            uint32_t slot = atomicAdd(&lcnt, 1u);    // <=1024 by construction
            skey[slot] = ((unsigned long long)kk << 32) |
                         (uint32_t)(~(uint32_t)i);
        }
    }
    __syncthreads();
    if (tid == 0 && lcnt) lbase = atomicAdd(&cand_cnt[p], lcnt);
    __syncthreads();
    const uint32_t n = lcnt;
    for (uint32_t e = tid; e < n; e += 1024) {
        uint32_t g = lbase + e;
        if (g < CAP) cand[(size_t)p * CAP + g] = skey[e];
    }

    __threadfence();                            // release cand/cand_cnt
    if (tid == 0)
        is_last = (atomicAdd(&done_seg[p], 1u) == BPP - 1);
    __syncthreads();
    if (!is_last) return;
    __threadfence();                            // acquire all segments

    // ---- select for problem p (R8 body, 1024 threads) ----
    const int b = p / NCLS;
    const int cnt = min((int)cand_cnt[p], CAP);
    skey[tid] = (tid < cnt) ? cand[(size_t)p * CAP + tid] : 0ull;
    __syncthreads();
    for (int k2 = 2; k2 <= CAP; k2 <<= 1)
        for (int j = k2 >> 1; j > 0; j >>= 1) {
            int ixj = tid ^ j;
            if (ixj > tid) {
                unsigned long long a = skey[tid], c = skey[ixj];
                bool up = ((tid & k2) == 0);
                if (up ? (a < c) : (a > c)) { skey[tid] = c; skey[ixj] = a; }
            }
            __syncthreads();
        }
    if (tid >= PRE) return;
    unsigned long long key = skey[tid];
    double* D = boxdata + (size_t)(p * PRE + tid) * 20;
    float* S = screen + (size_t)(p * PRE + tid) * 8;
    if (key == 0ull) {                          // defensive
        cand_idx[p * PRE + tid] = 0;
        cand_score[p * PRE + tid] = -1.0f;
        #pragma unroll
        for (int m = 0; m < 20; ++m) D[m] = 0.0;
        #pragma unroll
        for (int m = 0; m < 8; ++m) S[m] = 0.0f;
        return;
    }
    uint32_t idx = ~((uint32_t)key);
    uint32_t ov = (uint32_t)(key >> 32);
    uint32_t ub = (ov & 0x80000000u) ? (ov ^ 0x80000000u) : ~ov;
    float sc = __uint_as_float(ub);
    cand_idx[p * PRE + tid] = idx;
    cand_score[p * PRE + tid] = sc;

    const float* bp = boxes + ((size_t)b * NPTS + idx) * 7;
    double x = bp[0], y = bp[1], z = bp[2];
    double dx = bp[3], dy = bp[4], dz = bp[5], r = bp[6];
    double c = cos(r), s = sin(r);
    double hx = 0.5 * dx, hy = 0.5 * dy;
    double zlo = z - 0.5 * dz, zhi = z + 0.5 * dz;
    double rad = sqrt(hx * hx + hy * hy);
    D[0] = x; D[1] = y; D[2] = c; D[3] = s; D[4] = hx; D[5] = hy;
    D[6] = zlo; D[7] = zhi; D[8] = dx * dy * dz; D[9] = rad;
    const double lxs[4] = { hx, -hx, -hx,  hx };
    const double lys[4] = { hy,  hy, -hy, -hy };
    #pragma unroll
    for (int m = 0; m < 4; ++m) {
        D[10 + m] = x + lxs[m] * c - lys[m] * s;
        D[14 + m] = y + lxs[m] * s + lys[m] * c;
    }
    S[0] = (float)x; S[1] = (float)y; S[2] = (float)zlo; S[3] = (float)zhi;
    S[4] = (float)rad; S[5] = 0.0f; S[6] = 0.0f; S[7] = 0.0f;
}

// K3: fused f32 screen + wave-parallel exact f64 IoU; LAST block of each
// problem (576 blocks/problem) runs the greedy NMS + padded output.
// Replaces R8's iou_fused + nms_out dispatches.
__global__ __launch_bounds__(256) void iou_nms_kernel(
    const float* __restrict__ boxes, const float* __restrict__ screen,
    const double* __restrict__ boxdata, unsigned long long* __restrict__ mask,
    uint32_t* __restrict__ done_iou, const uint32_t* __restrict__ cand_idx,
    const float* __restrict__ cand_score, float* __restrict__ out)
{
    __shared__ unsigned long long sh_smask[PRE * 8];   // 32 KB (nms phase)
    __shared__ float sh_sscore[PRE];
    __shared__ int sh_slist[POST];
    __shared__ int sh_scnt;
    __shared__ uint32_t is_last;

    const int tid = threadIdx.x;
    const int lane = tid & 63;
    const int W = blockIdx.x * 4 + (tid >> 6);
    const int prob = W / WAVES_PER_PROB;       // block-uniform (576 | bound)
    {
        int t = W - prob * WAVES_PER_PROB;
        int cell = t >> 6, r = t & 63;
        int wi = 0;
        while (cell >= 8 - wi) { cell -= 8 - wi; ++wi; }
        const int wj = wi + cell;
        const int bi = wi * 64 + r;
        const int j = wj * 64 + lane;

        bool surv = false;
        {
            const float* SA = screen + (size_t)(prob * PRE + bi) * 8;
            const float* SB = screen + (size_t)(prob * PRE + j) * 8;
            if (j > bi) {
                float4 a4 = *(const float4*)SA;       // x,y,zlo,zhi
                float4 b4 = *(const float4*)SB;
                float hz = fminf(a4.w, b4.w) - fmaxf(a4.z, b4.z);
                if (hz > 0.0f) {
                    float ddx = a4.x - b4.x, ddy = a4.y - b4.y;
                    float rs = SA[4] + SB[4] + 0.01f;
                    surv = (ddx * ddx + ddy * ddy <= rs * rs);
                }
            }
        }
        unsigned long long sm = __ballot(surv);
        unsigned long long supw = 0ull;
        const double* A = boxdata + (size_t)(prob * PRE + bi) * 20;

        while (sm) {
            int jb = __ffsll(sm) - 1;
            sm &= sm - 1ull;
            const int bj = wj * 64 + jb;
            const double* B = boxdata + (size_t)(prob * PRE + bj) * 20;

            // lane owns one candidate point: 0-3 A-corners, 4-7 B-corners,
            // 8-23 edge intersections (reference construction order)
            double PX = 0.0, PY = 0.0;
            bool valid = false;
            if (lane < 8) {
                const double* S = (lane < 4) ? A : B;
                const double* O = (lane < 4) ? B : A;
                int m = lane & 3;
                PX = S[10 + m]; PY = S[14 + m];
                double rx = PX - O[0], ry = PY - O[1];
                double u =  rx * O[2] + ry * O[3];
                double v = -rx * O[3] + ry * O[2];
                valid = (fabs(u) <= O[4] + 1e-5) && (fabs(v) <= O[5] + 1e-5);
            } else if (lane < 24) {
                int e = lane - 8, m = e >> 2, nn = e & 3;
                double ax = A[10 + m], ay = A[14 + m];
                double rax = A[10 + ((m + 1) & 3)] - ax;
                double ray = A[14 + ((m + 1) & 3)] - ay;
                double bx = B[10 + nn], by = B[14 + nn];
                double rbx = B[10 + ((nn + 1) & 3)] - bx;
                double rby = B[14 + ((nn + 1) & 3)] - by;
                double d = rax * rby - ray * rbx;
                if (fabs(d) > 1e-8) {
                    double qx = bx - ax, qy = by - ay;
                    double tt = (qx * rby - qy * rbx) / d;
                    double uu = (qx * ray - qy * rax) / d;
                    valid = (tt >= 0.0 && tt <= 1.0 && uu >= 0.0 && uu <= 1.0);
                    PX = ax + tt * rax; PY = ay + tt * ray;
                }
            }
            if (!valid) { PX = 0.0; PY = 0.0; }

            unsigned long long bal = __ballot(valid);  // lanes 0-23 only
            int cnt = __popcll(bal);
            double sx = PX, sy = PY;
            #pragma unroll
            for (int off = 16; off; off >>= 1) {       // 32-group butterfly
                sx += __shfl_xor(sx, off);
                sy += __shfl_xor(sy, off);
            }
            int cdiv = cnt > 0 ? cnt : 1;              // ref: / max(cnt,1)
            double cxc = sx / cdiv, cyc = sy / cdiv;

            double ang = valid ? atan2(PY - cyc, PX - cxc) : 1e9;
            int sidx = lane;

            // 32-lane bitonic sort asc by (ang, sidx) == numpy stable argsort
            #pragma unroll
            for (int k = 2; k <= 32; k <<= 1) {
                #pragma unroll
                for (int jj = k >> 1; jj > 0; jj >>= 1) {
                    double oang = __shfl_xor(ang, jj);
                    double opx  = __shfl_xor(PX, jj);
                    double opy  = __shfl_xor(PY, jj);
                    int    oidx = __shfl_xor(sidx, jj);
                    bool iLow = (lane & jj) == 0;
                    bool dirUp = (lane & k) == 0;
                    bool mineFirst = (ang < oang) ||
                                     (ang == oang && sidx < oidx);
                    bool keepMine = (mineFirst == (iLow == dirUp));
                    if (!keepMine) { ang = oang; PX = opx; PY = opy; sidx = oidx; }
                }
            }

            // centered shoelace over sorted lanes [0, cnt)  (cnt <= 24)
            double nxp = __shfl(PX, (lane + 1) & 31);
            double nyp = __shfl(PY, (lane + 1) & 31);
            double fx  = __shfl(PX, 0);
            double fy  = __shfl(PY, 0);
            bool lastl = (lane == cnt - 1);
            double qx = lastl ? fx : nxp, qy = lastl ? fy : nyp;
            double contrib = 0.0;
            if (lane < cnt)
                contrib = (PX - cxc) * (qy - cyc) - (PY - cyc) * (qx - cxc);
            #pragma unroll
            for (int off = 16; off; off >>= 1)
                contrib += __shfl_xor(contrib, off);
            double inter = (cnt >= 3) ? 0.5 * fabs(contrib) : 0.0;

            if (lane == 0) {
                double zt = fmin(A[7], B[7]);
                double zb = fmax(A[6], B[6]);
                double hz = zt - zb;
                bool sup = false;
                if (hz > 0.0) {
                    double i3 = inter * hz;
                    double den = A[8] + B[8] - i3;
                    if (den < 1e-8) den = 1e-8;
                    sup = (i3 / den) > (double)NMS_TH;
                }
                if (sup) supw |= 1ull << jb;
            }
        }

        if (lane == 0)
            mask[(size_t)(prob * PRE + bi) * 8 + wj] = supw;   // exclusive
    }

    __threadfence();                            // release mask words
    if (tid == 0)
        is_last = (atomicAdd(&done_iou[prob], 1u) == BLKS_PER_PROB - 1);
    __syncthreads();
    if (!is_last) return;
    __threadfence();                            // acquire all mask words

    // ---- NMS + output for `prob` (R8 body) ----
    const int p = prob;
    const int b = p / NCLS, k = p % NCLS;
    for (int w = tid; w < PRE * 8; w += 256)
        sh_smask[w] = mask[(size_t)p * PRE * 8 + w];
    for (int i = tid; i < PRE; i += 256)
        sh_sscore[i] = cand_score[p * PRE + i];
    __syncthreads();

    // Wave-parallel greedy scan; early break at c==POST. Garbage bits in
    // lower-triangle mask words only mark columns j<i (already decided).
    if (tid < 64) {
        uint32_t supbits = 0;
        int c = 0;
        for (int i = 0; i < PRE; ++i) {
            uint32_t sb = (uint32_t)__shfl((int)supbits, i & 63);
            bool sup_i = (sb >> (i >> 6)) & 1u;
            float sc = sh_sscore[i];
            bool keep = (sc >= SCORE_TH) && !sup_i;
            if (keep) {
                if (tid == 0) sh_slist[c] = i;
                ++c;
                if (c >= POST) break;
                #pragma unroll
                for (int w = 0; w < 8; ++w) {
                    unsigned long long m = sh_smask[i * 8 + w];
                    supbits |= (uint32_t)((m >> tid) & 1ull) << w;
                }
            }
        }
        if (tid == 0) sh_scnt = c;
    }
    __syncthreads();

    const int cnt = sh_scnt;
    for (int t = tid; t < POST; t += 256) {
        int row = b * (NCLS * POST) + k * POST + t;          // 0..599
        float* ob = out + (size_t)row * 7;
        float* os = out + (size_t)NB * NCLS * POST * 7 + row;
        float* ol = out + (size_t)NB * NCLS * POST * 7 +
                    (size_t)NB * NCLS * POST + row;
        if (t < cnt) {
            int r = sh_slist[t];
            uint32_t idx = cand_idx[p * PRE + r];
            const float* bp = boxes + ((size_t)b * NPTS + idx) * 7;
            #pragma unroll
            for (int c7 = 0; c7 < 7; ++c7) ob[c7] = bp[c7];
            *os = sh_sscore[r];
            *ol = (float)(k + 1);
        } else {
            #pragma unroll
            for (int c7 = 0; c7 < 7; ++c7) ob[c7] = 0.0f;
            *os = 0.0f;
            *ol = 0.0f;
        }
    }
}

extern "C" void kernel_launch(void* const* d_in, const int* in_sizes, int n_in,
                              void* d_out, int out_size, void* d_ws, size_t ws_size,
                              hipStream_t stream)
{
    (void)in_sizes; (void)n_in; (void)out_size; (void)ws_size;
    const float* cls   = (const float*)d_in[0];   // (2,100000,3) f32
    const float* boxes = (const float*)d_in[1];   // (2,100000,7) f32
    float* out = (float*)d_out;

    char* ws = (char*)d_ws;
    uint32_t* hist        = (uint32_t*)(ws);
    uint32_t* cand_cnt    = (uint32_t*)(ws + 9216);
    uint32_t* done_hist   = (uint32_t*)(ws + 9280);
    uint32_t* done_seg    = (uint32_t*)(ws + 9344);
    uint32_t* done_iou    = (uint32_t*)(ws + 9408);
    uint32_t* pivots      = (uint32_t*)(ws + 9472);
    unsigned long long* mask = (unsigned long long*)(ws + 9536);
    unsigned long long* cand = (unsigned long long*)(ws + 206144);
    uint32_t* cand_idx    = (uint32_t*)(ws + 255296);
    float*    cand_score  = (float*)   (ws + 267584);
    double*   boxdata     = (double*)  (ws + 279872);
    float*    screen      = (float*)   (ws + 771392);
    float*    sf          = (float*)   (ws + 869696);

    // zero hist + cand_cnt + completion counters (ws poisoned 0xAA each call)
    hipMemsetAsync(ws, 0, 9472, stream);

    hipLaunchKernelGGL(hist_pivot_kernel, dim3(NB * BPP), dim3(1024), 0, stream,
                       cls, sf, hist, done_hist, pivots);
    hipLaunchKernelGGL(compact_select_kernel, dim3(NPROB * BPP), dim3(1024),
                       0, stream, cls, boxes, sf, pivots, cand_cnt, cand,
                       done_seg, cand_idx, cand_score, boxdata, screen);
    hipLaunchKernelGGL(iou_nms_kernel, dim3(NPROB * BLKS_PER_PROB), dim3(256),
                       0, stream, boxes, screen, boxdata, mask, done_iou,
                       cand_idx, cand_score, out);
}

// Round 11
// 145.860 us; speedup vs baseline: 3.7175x; 3.7175x over previous
//
#include <hip/hip_runtime.h>
#include <cstdint>

#define NCLS 3
#define NPTS 100000
#define NB 2
#define PRE 512
#define POST 100
#define SCORE_TH 0.1f
#define NMS_TH 0.25
#define CAP 1024            // candidate buffer per problem (expect ~690)
#define BPP 98              // 1024-point chunks per plane (98*1024 >= 100000)
#define NBINS 384           // fast-key bins: (key>>17) - (0xBD000000>>17)
#define BIN_SH 17
#define BIN_OFFW (0xBD000000u >> BIN_SH)
#define FMARG 2e-5f         // 2x bound on |f32 sigmoid - f64 sigmoid| (<=1e-6)
#define NPROB (NB * NCLS)
#define WAVES_PER_PROB 2304  // 36 upper-tri 64x64 cells x 64 rows
#define HPB (NCLS * NBINS)   // 1152 partial-hist entries per hist block

// ---------------- ws layout (bytes) ---------------- (NO memset, NO fences)
// cand_cnt  : uint32 [6] (pad 64)   @ 0           (zeroed by hist block 0;
//                                                   visible via launch bndry)
// mask      : uint64 [6*PRE*8]      @ 64          (196,608; upper-tri words
//                                                   always stored by iou_fused;
//                                                   lower-tri garbage harmless)
// cand      : uint64 [6*CAP]        @ 196,672     (49,152)
// cand_idx  : uint32 [6*PRE]        @ 245,824     (12,288)
// cand_scr  : float  [6*PRE]        @ 258,112     (12,288)
// boxdata   : double [6*PRE*20]     @ 270,400     (491,520)
// screen    : float  [6*PRE*8]      @ 761,920     (98,304)
// sf        : float  [6*NPTS]       @ 860,224     (2,400,000)  plane-major
// hist_part : uint32 [196*1152]     @ 3,260,224   (903,168)
// total ~4.16 MB

__device__ __forceinline__ uint32_t score_key(float x)
{
    // EXACT path: f64 sigmoid rounded to f32 == reference (absmax 0.0 R1-R10)
    double sd = 1.0 / (1.0 + exp(-(double)x));
    float s = (float)sd;
    if (!(s >= SCORE_TH)) s = -1.0f;
    uint32_t u = __float_as_uint(s);
    return (u & 0x80000000u) ? ~u : (u | 0x80000000u);
}

__device__ __forceinline__ float fast_sig(float x)
{
    return 1.0f / (1.0f + __expf(-x));
}

// monotone bin of a (possibly margin-adjusted) f32 score
__device__ __forceinline__ int fast_bin(float s)
{
    float v = (s >= SCORE_TH) ? s : -1.0f;
    uint32_t u = __float_as_uint(v);
    uint32_t kk = (u & 0x80000000u) ? ~u : (u | 0x80000000u);
    int b = (int)(kk >> BIN_SH) - (int)BIN_OFFW;
    return b < 0 ? 0 : (b > NBINS - 1 ? NBINS - 1 : b);
}

// K1: fast sigmoid + per-block partial histograms (plain stores -> no global
// pre-zero). Block 0 also zeros cand_cnt (plain stores; the K1->K2 launch
// boundary provides visibility -- no fences: R10 showed device fences and
// single-cacheline completion atomics cost 100s of us on 8 XCDs).
__global__ __launch_bounds__(1024) void hist_kernel(
    const float* __restrict__ cls, float* __restrict__ sf,
    uint32_t* __restrict__ hist_part, uint32_t* __restrict__ cand_cnt)
{
    __shared__ uint32_t lh[HPB];
    for (int t = threadIdx.x; t < HPB; t += 1024) lh[t] = 0;
    __syncthreads();
    const int b = blockIdx.x / BPP, cb = blockIdx.x % BPP;
    const int i = cb * 1024 + threadIdx.x;
    if (i < NPTS) {
        const float* cp = cls + ((size_t)b * NPTS + i) * NCLS;
        #pragma unroll
        for (int k = 0; k < NCLS; ++k) {
            float sfv = fast_sig(cp[k]);
            sf[(size_t)(b * NCLS + k) * NPTS + i] = sfv;
            atomicAdd(&lh[k * NBINS + fast_bin(sfv)], 1u);
        }
    }
    __syncthreads();
    uint32_t* P = hist_part + (size_t)blockIdx.x * HPB;
    for (int t = threadIdx.x; t < HPB; t += 1024) P[t] = lh[t];
    if (blockIdx.x == 0 && threadIdx.x < NPROB) cand_cnt[threadIdx.x] = 0;
}

// K2: per-block pivot recompute (same reduction+scan as R8's pivot_kernel,
// bit-identical result) + compact survivors. Merging removes the 6-block
// pivot dispatch. One global atomicAdd per block (588, spread addresses).
__global__ __launch_bounds__(1024) void compact_kernel(
    const float* __restrict__ cls, const float* __restrict__ sf,
    const uint32_t* __restrict__ hist_part, uint32_t* __restrict__ cand_cnt,
    unsigned long long* __restrict__ cand)
{
    __shared__ uint32_t bins[NBINS];
    __shared__ uint32_t csum[128];
    __shared__ uint32_t sh_pb;
    __shared__ unsigned long long stage[1024];
    __shared__ uint32_t lcnt, lbase;

    const int p = blockIdx.x / BPP, cb = blockIdx.x % BPP;
    const int b = p / NCLS, k = p % NCLS;
    const int tid = threadIdx.x;

    // ---- pivot for problem p (R8 pivot body) ----
    if (tid < NBINS) {
        uint32_t s = 0;
        const uint32_t* base =
            hist_part + (size_t)(b * BPP) * HPB + k * NBINS + tid;
        for (int c = 0; c < BPP; ++c) s += base[(size_t)c * HPB];
        bins[tid] = s;
    }
    if (tid == 0) lcnt = 0;
    __syncthreads();
    if (tid < 128)
        csum[tid] = bins[tid * 3] + bins[tid * 3 + 1] + bins[tid * 3 + 2];
    __syncthreads();
    if (tid == 0) {
        int cum = 0, cchunk = 0;
        for (int c = 127; c >= 0; --c) {
            if (cum + (int)csum[c] >= PRE) { cchunk = c; break; }
            cum += (int)csum[c];
        }
        uint32_t pb = 0;
        for (int bin = cchunk * 3 + 2; bin >= cchunk * 3; --bin) {
            int h = (int)bins[bin];
            if (cum + h >= PRE) { pb = (uint32_t)bin; break; }
            cum += h;
        }
        sh_pb = pb;
    }
    __syncthreads();
    const uint32_t pb = sh_pb;

    // ---- compact this segment (R8 body) ----
    const int i = cb * 1024 + tid;
    if (i < NPTS) {
        float sfv = sf[(size_t)p * NPTS + i];      // identical bits to K1's
        if ((uint32_t)fast_bin(sfv + FMARG) >= pb) {
            uint32_t kk = score_key(cls[((size_t)b * NPTS + i) * NCLS + k]);
            uint32_t slot = atomicAdd(&lcnt, 1u);  // <=1024 by construction
            stage[slot] = ((unsigned long long)kk << 32) |
                          (uint32_t)(~(uint32_t)i);
        }
    }
    __syncthreads();
    if (tid == 0 && lcnt) lbase = atomicAdd(&cand_cnt[p], lcnt);
    __syncthreads();
    const uint32_t n = lcnt;
    if (n) {
        const uint32_t base = lbase;
        for (uint32_t e = tid; e < n; e += 1024) {
            uint32_t g = base + e;
            if (g < CAP) cand[(size_t)p * CAP + g] = stage[e];
        }
    }
}

__global__ __launch_bounds__(1024) void select_kernel(
    const float* __restrict__ boxes, const unsigned long long* __restrict__ cand,
    const uint32_t* __restrict__ cand_cnt, uint32_t* __restrict__ cand_idx,
    float* __restrict__ cand_score, double* __restrict__ boxdata,
    float* __restrict__ screen)
{
    const int p = blockIdx.x;
    const int b = p / NCLS;
    const int tid = threadIdx.x;
    __shared__ unsigned long long skey[CAP];
    const int cnt = min((int)cand_cnt[p], CAP);
    skey[tid] = (tid < cnt) ? cand[(size_t)p * CAP + tid] : 0ull;
    __syncthreads();

    // bitonic sort, one slot per thread, overall descending
    for (int k2 = 2; k2 <= CAP; k2 <<= 1)
        for (int j = k2 >> 1; j > 0; j >>= 1) {
            int ixj = tid ^ j;
            if (ixj > tid) {
                unsigned long long a = skey[tid], c = skey[ixj];
                bool up = ((tid & k2) == 0);
                if (up ? (a < c) : (a > c)) { skey[tid] = c; skey[ixj] = a; }
            }
            __syncthreads();
        }

    // epilogue: top-512 decode + f64 geometry + f32 screen
    if (tid >= PRE) return;
    unsigned long long key = skey[tid];
    double* D = boxdata + (size_t)(p * PRE + tid) * 20;
    float* S = screen + (size_t)(p * PRE + tid) * 8;
    if (key == 0ull) {                     // defensive: can't happen normally
        cand_idx[p * PRE + tid] = 0;
        cand_score[p * PRE + tid] = -1.0f;
        #pragma unroll
        for (int m = 0; m < 20; ++m) D[m] = 0.0;
        #pragma unroll
        for (int m = 0; m < 8; ++m) S[m] = 0.0f;
        return;
    }
    uint32_t idx = ~((uint32_t)key);
    uint32_t ov = (uint32_t)(key >> 32);
    uint32_t ub = (ov & 0x80000000u) ? (ov ^ 0x80000000u) : ~ov;
    float sc = __uint_as_float(ub);
    cand_idx[p * PRE + tid] = idx;
    cand_score[p * PRE + tid] = sc;

    const float* bp = boxes + ((size_t)b * NPTS + idx) * 7;
    double x = bp[0], y = bp[1], z = bp[2];
    double dx = bp[3], dy = bp[4], dz = bp[5], r = bp[6];
    double c = cos(r), s = sin(r);
    double hx = 0.5 * dx, hy = 0.5 * dy;
    double zlo = z - 0.5 * dz, zhi = z + 0.5 * dz;
    double rad = sqrt(hx * hx + hy * hy);
    D[0] = x; D[1] = y; D[2] = c; D[3] = s; D[4] = hx; D[5] = hy;
    D[6] = zlo; D[7] = zhi; D[8] = dx * dy * dz; D[9] = rad;
    const double lxs[4] = { hx, -hx, -hx,  hx };
    const double lys[4] = { hy,  hy, -hy, -hy };
    #pragma unroll
    for (int m = 0; m < 4; ++m) {
        D[10 + m] = x + lxs[m] * c - lys[m] * s;
        D[14 + m] = y + lxs[m] * s + lys[m] * c;
    }
    S[0] = (float)x; S[1] = (float)y; S[2] = (float)zlo; S[3] = (float)zhi;
    S[4] = (float)rad; S[5] = 0.0f; S[6] = 0.0f; S[7] = 0.0f;
}

// Fused screen + exact IoU. One wave per (prob, cell, row): wave owns mask
// word (prob,i,wj) exclusively and ALWAYS stores it (even 0) -> mask needs
// no pre-zero. Lower-triangle words stay garbage: bits there mark columns
// j<i, which the greedy scan has already passed -- provably no effect.
__global__ __launch_bounds__(256) void iou_fused_kernel(
    const float* __restrict__ screen, const double* __restrict__ boxdata,
    unsigned long long* __restrict__ mask)
{
    const int W = blockIdx.x * 4 + (threadIdx.x >> 6);
    const int lane = threadIdx.x & 63;
    const int prob = W / WAVES_PER_PROB;
    int t = W - prob * WAVES_PER_PROB;
    int cell = t >> 6, r = t & 63;
    int wi = 0;
    while (cell >= 8 - wi) { cell -= 8 - wi; ++wi; }
    const int wj = wi + cell;
    const int bi = wi * 64 + r;
    const int j = wj * 64 + lane;

    bool surv = false;
    {
        const float* SA = screen + (size_t)(prob * PRE + bi) * 8; // wave-uniform
        const float* SB = screen + (size_t)(prob * PRE + j) * 8;
        if (j > bi) {
            float4 a4 = *(const float4*)SA;           // x,y,zlo,zhi
            float4 b4 = *(const float4*)SB;
            float hz = fminf(a4.w, b4.w) - fmaxf(a4.z, b4.z);
            if (hz > 0.0f) {
                float ddx = a4.x - b4.x, ddy = a4.y - b4.y;
                float rs = SA[4] + SB[4] + 0.01f;
                surv = (ddx * ddx + ddy * ddy <= rs * rs);
            }
        }
    }
    unsigned long long sm = __ballot(surv);   // wave-uniform survivor set
    unsigned long long supw = 0ull;
    const double* A = boxdata + (size_t)(prob * PRE + bi) * 20;

    while (sm) {
        int jb = __ffsll(sm) - 1;
        sm &= sm - 1ull;
        const int bj = wj * 64 + jb;
        const double* B = boxdata + (size_t)(prob * PRE + bj) * 20;

        // lane owns one candidate point: 0-3 A-corners, 4-7 B-corners,
        // 8-23 edge intersections (reference construction order)
        double PX = 0.0, PY = 0.0;
        bool valid = false;
        if (lane < 8) {
            const double* S = (lane < 4) ? A : B;
            const double* O = (lane < 4) ? B : A;
            int m = lane & 3;
            PX = S[10 + m]; PY = S[14 + m];
            double rx = PX - O[0], ry = PY - O[1];
            double u =  rx * O[2] + ry * O[3];
            double v = -rx * O[3] + ry * O[2];
            valid = (fabs(u) <= O[4] + 1e-5) && (fabs(v) <= O[5] + 1e-5);
        } else if (lane < 24) {
            int e = lane - 8, m = e >> 2, nn = e & 3;
            double ax = A[10 + m], ay = A[14 + m];
            double rax = A[10 + ((m + 1) & 3)] - ax;
            double ray = A[14 + ((m + 1) & 3)] - ay;
            double bx = B[10 + nn], by = B[14 + nn];
            double rbx = B[10 + ((nn + 1) & 3)] - bx;
            double rby = B[14 + ((nn + 1) & 3)] - by;
            double d = rax * rby - ray * rbx;
            if (fabs(d) > 1e-8) {
                double qx = bx - ax, qy = by - ay;
                double tt = (qx * rby - qy * rbx) / d;
                double uu = (qx * ray - qy * rax) / d;
                valid = (tt >= 0.0 && tt <= 1.0 && uu >= 0.0 && uu <= 1.0);
                PX = ax + tt * rax; PY = ay + tt * ray;
            }
        }
        if (!valid) { PX = 0.0; PY = 0.0; }

        unsigned long long bal = __ballot(valid);  // valid only in lanes 0-23
        int cnt = __popcll(bal);
        double sx = PX, sy = PY;          // invalid lanes contribute 0
        #pragma unroll
        for (int off = 16; off; off >>= 1) {       // 32-group butterfly
            sx += __shfl_xor(sx, off);
            sy += __shfl_xor(sy, off);
        }
        int cdiv = cnt > 0 ? cnt : 1;     // ref: / max(cnt, 1)
        double cxc = sx / cdiv, cyc = sy / cdiv;

        double ang = valid ? atan2(PY - cyc, PX - cxc) : 1e9;
        int sidx = lane;                  // construction order == ref slots

        // 32-lane bitonic sort asc by (ang, sidx) == numpy stable argsort
        #pragma unroll
        for (int k = 2; k <= 32; k <<= 1) {
            #pragma unroll
            for (int jj = k >> 1; jj > 0; jj >>= 1) {
                double oang = __shfl_xor(ang, jj);
                double opx  = __shfl_xor(PX, jj);
                double opy  = __shfl_xor(PY, jj);
                int    oidx = __shfl_xor(sidx, jj);
                bool iLow = (lane & jj) == 0;
                bool dirUp = (lane & k) == 0;
                bool mineFirst = (ang < oang) || (ang == oang && sidx < oidx);
                bool keepMine = (mineFirst == (iLow == dirUp));
                if (!keepMine) { ang = oang; PX = opx; PY = opy; sidx = oidx; }
            }
        }

        // centered shoelace over sorted lanes [0, cnt)  (cnt <= 24 < 32)
        double nxp = __shfl(PX, (lane + 1) & 31);
        double nyp = __shfl(PY, (lane + 1) & 31);
        double fx  = __shfl(PX, 0);
        double fy  = __shfl(PY, 0);
        bool last = (lane == cnt - 1);
        double qx = last ? fx : nxp, qy = last ? fy : nyp;
        double contrib = 0.0;
        if (lane < cnt)
            contrib = (PX - cxc) * (qy - cyc) - (PY - cyc) * (qx - cxc);
        #pragma unroll
        for (int off = 16; off; off >>= 1) contrib += __shfl_xor(contrib, off);
        double inter = (cnt >= 3) ? 0.5 * fabs(contrib) : 0.0;

        if (lane == 0) {
            double zt = fmin(A[7], B[7]);
            double zb = fmax(A[6], B[6]);
            double hz = zt - zb;
            bool sup = false;
            if (hz > 0.0) {
                double i3 = inter * hz;
                double den = A[8] + B[8] - i3;
                if (den < 1e-8) den = 1e-8;
                sup = (i3 / den) > (double)NMS_TH;
            }
            if (sup) supw |= 1ull << jb;
        }
    }

    if (lane == 0)
        mask[(size_t)(prob * PRE + bi) * 8 + wj] = supw;   // exclusive word
}

__global__ __launch_bounds__(256) void nms_out_kernel(
    const float* __restrict__ boxes, const uint32_t* __restrict__ cand_idx,
    const float* __restrict__ cand_score,
    const unsigned long long* __restrict__ mask, float* __restrict__ out)
{
    const int p = blockIdx.x;
    const int b = p / NCLS, k = p % NCLS;
    const int tid = threadIdx.x;

    __shared__ unsigned long long smask[PRE * 8];   // 32 KB
    __shared__ float sscore[PRE];
    __shared__ int slist[POST];
    __shared__ int scnt;

    for (int w = tid; w < PRE * 8; w += 256)
        smask[w] = mask[(size_t)p * PRE * 8 + w];
    for (int i = tid; i < PRE; i += 256)
        sscore[i] = cand_score[p * PRE + i];
    __syncthreads();

    // Wave-parallel greedy scan; early break at c==POST. Garbage bits in
    // lower-triangle mask words only mark columns j<i (already decided).
    if (tid < 64) {
        const int lane = tid;
        uint32_t supbits = 0;
        int c = 0;
        for (int i = 0; i < PRE; ++i) {
            uint32_t sb = (uint32_t)__shfl((int)supbits, i & 63);
            bool sup_i = (sb >> (i >> 6)) & 1u;
            float sc = sscore[i];                      // LDS broadcast
            bool keep = (sc >= SCORE_TH) && !sup_i;    // wave-uniform
            if (keep) {
                if (lane == 0) slist[c] = i;
                ++c;
                if (c >= POST) break;
                #pragma unroll
                for (int w = 0; w < 8; ++w) {
                    unsigned long long m = smask[i * 8 + w];  // broadcast
                    supbits |= (uint32_t)((m >> lane) & 1ull) << w;
                }
            }
        }
        if (lane == 0) scnt = c;
    }
    __syncthreads();

    const int cnt = scnt;
    for (int t = tid; t < POST; t += 256) {
        int row = b * (NCLS * POST) + k * POST + t;          // 0..599
        float* ob = out + (size_t)row * 7;
        float* os = out + (size_t)NB * NCLS * POST * 7 + row;
        float* ol = out + (size_t)NB * NCLS * POST * 7 + (size_t)NB * NCLS * POST + row;
        if (t < cnt) {
            int r = slist[t];
            uint32_t idx = cand_idx[p * PRE + r];
            const float* bp = boxes + ((size_t)b * NPTS + idx) * 7;
            #pragma unroll
            for (int c7 = 0; c7 < 7; ++c7) ob[c7] = bp[c7];
            *os = sscore[r];
            *ol = (float)(k + 1);
        } else {
            #pragma unroll
            for (int c7 = 0; c7 < 7; ++c7) ob[c7] = 0.0f;
            *os = 0.0f;
            *ol = 0.0f;
        }
    }
}

extern "C" void kernel_launch(void* const* d_in, const int* in_sizes, int n_in,
                              void* d_out, int out_size, void* d_ws, size_t ws_size,
                              hipStream_t stream)
{
    (void)in_sizes; (void)n_in; (void)out_size; (void)ws_size;
    const float* cls   = (const float*)d_in[0];   // (2,100000,3) f32
    const float* boxes = (const float*)d_in[1];   // (2,100000,7) f32
    float* out = (float*)d_out;

    char* ws = (char*)d_ws;
    uint32_t* cand_cnt    = (uint32_t*)(ws);
    unsigned long long* mask = (unsigned long long*)(ws + 64);
    unsigned long long* cand = (unsigned long long*)(ws + 196672);
    uint32_t* cand_idx    = (uint32_t*)(ws + 245824);
    float*    cand_score  = (float*)   (ws + 258112);
    double*   boxdata     = (double*)  (ws + 270400);
    float*    screen      = (float*)   (ws + 761920);
    float*    sf          = (float*)   (ws + 860224);
    uint32_t* hist_part   = (uint32_t*)(ws + 3260224);

    // No memset, no fences, no cross-block sync: launch boundaries only.

    hipLaunchKernelGGL(hist_kernel, dim3(NB * BPP), dim3(1024), 0, stream,
                       cls, sf, hist_part, cand_cnt);
    hipLaunchKernelGGL(compact_kernel, dim3(NPROB * BPP), dim3(1024), 0, stream,
                       cls, sf, hist_part, cand_cnt, cand);
    hipLaunchKernelGGL(select_kernel, dim3(NPROB), dim3(1024), 0, stream,
                       boxes, cand, cand_cnt, cand_idx, cand_score, boxdata, screen);
    hipLaunchKernelGGL(iou_fused_kernel, dim3(NPROB * WAVES_PER_PROB / 4),
                       dim3(256), 0, stream, screen, boxdata, mask);
    hipLaunchKernelGGL(nms_out_kernel, dim3(NPROB), dim3(256), 0, stream,
                       boxes, cand_idx, cand_score, mask, out);
}